// Round 4
// baseline (3802.911 us; speedup 1.0000x reference)
//
#include <hip/hip_runtime.h>
#include <math.h>

// ---------------------------------------------------------------------------
// ImitateJoint: 12-step beam-search LSTM decoder.
// B=64 images, K=8 beams (BK=512 rows), T=12, H=2048, IN=2048, D=400, E=128.
// Round 4: GEMM K-loop restructured m97-style: global_load_lds (width=16)
// DMA staging of f32 operands, double-buffered LDS, ONE barrier per chunk
// (next chunk's DMA in flight during MFMA), f32->f16 hi/lo split done in
// registers after conflict-free ds_read_b128 fragment loads. 3-term MFMA
// (hi*hi + (hi*lo'+lo'*hi)/2048) keeps ~fp32 accuracy on the matrix pipe.
// Decision-critical math (softmax, Gumbel g, top-k, entropy) stays fp64.
// ---------------------------------------------------------------------------

#define BB   64
#define KK   8
#define TT   12
#define HH   2048
#define DD   400
#define EE   128
#define BKR  512          // B*K rows
#define G4   8192         // 4*H

// ---- workspace layout (byte offsets) --------------------------------------
static const size_t OFF_STATE = 0;                // doubles, 14272 used
static const size_t OFF_H     = 114688;           // float [512][2048]
static const size_t OFF_C     = 4308992;          // float [512][2048]
static const size_t ZERO_END  = 8503296;          // memset 0 .. here
static const size_t OFF_Z     = 8503296;          // float, up to 8 partials
static const size_t OFF_H2    = 42057728;         // float [512][2048]
static const size_t OFF_C2    = 46252032;         // float [512][2048]
static const size_t OFF_HD    = 50446336;         // float [512][2048]
static const size_t OFF_EMB   = 54640640;         // float [512][128]
static const size_t OFF_XFW   = 54902784;         // float [64][8192]
static const size_t OFF_BIAS  = 56999936;         // float [8192]
static const size_t OFF_LPT   = 57032704;         // double [512][400]
static const size_t OFF_GMAT  = 58671104;         // double [512][400]
static const size_t OFF_INTS  = 60309504;         // int [1024]
static const size_t WS_TOTAL  = 60313600;         // ~57.5 MB

#define SI_G    0
#define SI_LOGP 512
#define SI_SAMP 1024
#define SI_OUTS 7168
#define SI_ENT  13312
#define SI_WPQ  13376
#define SI_LGP  13824

using half8   = __attribute__((ext_vector_type(8))) _Float16;
using floatx4 = __attribute__((ext_vector_type(4))) float;

// async global->LDS, 16 B per lane; LDS dest = wave-uniform base + lane*16
__device__ __forceinline__ void dma16(const float* g, float* l)
{
    __builtin_amdgcn_global_load_lds(
        (const __attribute__((address_space(1))) void*)g,
        (__attribute__((address_space(3))) void*)l, 16, 0, 0);
}

// ---------------------------------------------------------------------------
// DMA-staged MFMA GEMM: C[z][512][N] = A[512,K]*B[N,K]^T partials (f32 out).
// Block 256 thr = 4 waves, tile 128x128, wave tile 64x64 = 4x4 of
// mfma_f32_16x16x32_f16 x 3 terms. BK=32. LDS 2 x (A 16KB | B 16KB).
// LDS granule g(r,q) = (r>>4)*128 + (q&1)*64 + (q>>1)*16 + (r&15)
// (granule = 16 B = 4 floats, q = k-quad 0..7). DMA instr i covers granules
// [i*64, i*64+64) -> per-lane global gather, LDS linear. Fragment reads are
// lane-consecutive b128 (stride-1, conflict-free).
// A: up to 3 concatenated f32 segments (seg1/seg2 share lda12); B: up to 2.
// Segment boundaries must be multiples of 32 (true for all calls).
// ---------------------------------------------------------------------------
__global__ __launch_bounds__(256, 2)
void ij_gemm_dma(const float* __restrict__ A0, const float* __restrict__ A1,
                 const float* __restrict__ A2, int kA1, int kA2,
                 int lda0, int lda12,
                 const float* __restrict__ B0, const float* __restrict__ B1,
                 int kB1, int ldb0, int ldb1,
                 float* __restrict__ C, int N, int Klen)
{
    __shared__ float lds[2][8192];    // [buf][ A 4096 floats | B 4096 floats ]

    const int tid = threadIdx.x;
    const int n0  = blockIdx.x * 128;
    const int m0  = blockIdx.y * 128;
    const int kstart = blockIdx.z * Klen;
    const int nch = Klen / 32;
    float* Cout = C + (size_t)blockIdx.z * ((size_t)512 * (size_t)N);

    const int w      = tid >> 6;
    const int wave_m = w & 1;
    const int wave_n = w >> 1;
    const int lane   = tid & 63;
    const int lo16   = lane & 15;
    const int oq     = lane >> 4;

    // DMA geometry: wave w issues instrs i = 4w..4w+3 for A and for B.
    // instr j: row = (2w + (j>>1))*16 + lo16 ; q = oq*2 + (j&1)
    const int rowL0 = (2 * w) * 16 + lo16;   // j = 0,1
    const int rowL1 = rowL0 + 16;            // j = 2,3
    const int aoff0s = (m0 + rowL0) * lda0,  aoff1s = (m0 + rowL1) * lda0;
    const int aoff0b = (m0 + rowL0) * lda12, aoff1b = (m0 + rowL1) * lda12;
    int brow0 = n0 + rowL0; if (brow0 > N - 1) brow0 = N - 1;   // clamp (N=400)
    int brow1 = n0 + rowL1; if (brow1 > N - 1) brow1 = N - 1;
    const int boff00 = brow0 * ldb0, boff10 = brow1 * ldb0;
    const int boff01 = brow0 * ldb1, boff11 = brow1 * ldb1;
    const int qk0 = oq * 8;                  // q*4 for j even; +4 for j odd

    auto issueDMA = [&](int c, int buf) {
        const int kb = kstart + c * 32;
        // A segment is uniform per chunk (boundaries are multiples of 32)
        const float* aseg; int asub; bool big;
        if (kb < kA1)      { aseg = A0; asub = kb;       big = false; }
        else if (kb < kA2) { aseg = A1; asub = kb - kA1; big = true; }
        else               { aseg = A2; asub = kb - kA2; big = true; }
        const int a0 = (big ? aoff0b : aoff0s) + asub;
        const int a1 = (big ? aoff1b : aoff1s) + asub;
        float* la = &lds[buf][0];
        dma16(aseg + a0 + qk0,     la + (4 * w + 0) * 256);
        dma16(aseg + a0 + qk0 + 4, la + (4 * w + 1) * 256);
        dma16(aseg + a1 + qk0,     la + (4 * w + 2) * 256);
        dma16(aseg + a1 + qk0 + 4, la + (4 * w + 3) * 256);
        const float* bseg; int bsub; bool bigB;
        if (kb < kB1) { bseg = B0; bsub = kb;       bigB = false; }
        else          { bseg = B1; bsub = kb - kB1; bigB = true; }
        const int b0 = (bigB ? boff01 : boff00) + bsub;
        const int b1 = (bigB ? boff11 : boff10) + bsub;
        float* lb = la + 4096;
        dma16(bseg + b0 + qk0,     lb + (4 * w + 0) * 256);
        dma16(bseg + b0 + qk0 + 4, lb + (4 * w + 1) * 256);
        dma16(bseg + b1 + qk0,     lb + (4 * w + 2) * 256);
        dma16(bseg + b1 + qk0 + 4, lb + (4 * w + 3) * 256);
    };

    floatx4 acc1[4][4], acc2[4][4];
#pragma unroll
    for (int i = 0; i < 4; ++i)
#pragma unroll
        for (int j = 0; j < 4; ++j) { acc1[i][j] = (floatx4)0.f; acc2[i][j] = (floatx4)0.f; }

    issueDMA(0, 0);
    for (int c = 0; c < nch; ++c) {
        __syncthreads();                  // compiler drains vmcnt -> chunk c ready
        if (c + 1 < nch) issueDMA(c + 1, (c + 1) & 1);   // in flight during MFMA

        const float* La = &lds[c & 1][0];
        const float* Lb = La + 4096;

        half8 Ahi[4], Alo[4];
#pragma unroll
        for (int mt = 0; mt < 4; ++mt) {
            const int g0 = (wave_m * 4 + mt) * 128 + oq * 16 + lo16;
            float4 f0 = *(const float4*)(La + g0 * 4);
            float4 f1 = *(const float4*)(La + (g0 + 64) * 4);
            float x[8] = {f0.x, f0.y, f0.z, f0.w, f1.x, f1.y, f1.z, f1.w};
            half8 hi, lo;
#pragma unroll
            for (int jj = 0; jj < 8; ++jj) {
                _Float16 h = (_Float16)x[jj];
                hi[jj] = h;
                lo[jj] = (_Float16)((x[jj] - (float)h) * 2048.0f);
            }
            Ahi[mt] = hi; Alo[mt] = lo;
        }
#pragma unroll
        for (int nt = 0; nt < 4; ++nt) {
            const int g0 = (wave_n * 4 + nt) * 128 + oq * 16 + lo16;
            float4 f0 = *(const float4*)(Lb + g0 * 4);
            float4 f1 = *(const float4*)(Lb + (g0 + 64) * 4);
            float x[8] = {f0.x, f0.y, f0.z, f0.w, f1.x, f1.y, f1.z, f1.w};
            half8 Bhi, Blo;
#pragma unroll
            for (int jj = 0; jj < 8; ++jj) {
                _Float16 h = (_Float16)x[jj];
                Bhi[jj] = h;
                Blo[jj] = (_Float16)((x[jj] - (float)h) * 2048.0f);
            }
#pragma unroll
            for (int mt = 0; mt < 4; ++mt) {
                acc1[mt][nt] = __builtin_amdgcn_mfma_f32_16x16x32_f16(Ahi[mt], Bhi, acc1[mt][nt], 0, 0, 0);
                acc2[mt][nt] = __builtin_amdgcn_mfma_f32_16x16x32_f16(Ahi[mt], Blo, acc2[mt][nt], 0, 0, 0);
                acc2[mt][nt] = __builtin_amdgcn_mfma_f32_16x16x32_f16(Alo[mt], Bhi, acc2[mt][nt], 0, 0, 0);
            }
        }
    }

    // epilogue: row = m0 + wave_m*64 + mt*16 + oq*4 + v ; col = n0 + wave_n*64 + nt*16 + lo16
    const float s = 1.0f / 2048.0f;
#pragma unroll
    for (int mt = 0; mt < 4; ++mt) {
        const int rbase = m0 + wave_m * 64 + mt * 16 + oq * 4;
#pragma unroll
        for (int nt = 0; nt < 4; ++nt) {
            const int col = n0 + wave_n * 64 + nt * 16 + lo16;
            if (col >= N) continue;
#pragma unroll
            for (int v = 0; v < 4; ++v) {
                float val = acc1[mt][nt][v] + acc2[mt][nt][v] * s;
                Cout[(size_t)(rbase + v) * N + col] = val;
            }
        }
    }
}

// ---------------------------------------------------------------------------
// fp32 vector GEMM (kept for the one-time xfW precompute, M=64).
// ---------------------------------------------------------------------------
#define FBM 128
#define FBN 64
#define FBK 16

__global__ __launch_bounds__(256, 2)
void ij_gemm_f32(const float* __restrict__ A0, const float* __restrict__ A1,
                 const float* __restrict__ A2, int kA1, int kA2,
                 int lda0, int lda1, int lda2,
                 const float* __restrict__ B0, const float* __restrict__ B1,
                 int kB1, int ldb0, int ldb1,
                 float* __restrict__ C, int M, int N, int Klen)
{
    __shared__ float As[2][FBK][FBM];
    __shared__ float Bs[2][FBK][FBN];

    const int tid = threadIdx.x;
    const int tx  = tid & 15;
    const int ty  = tid >> 4;
    const int n0  = blockIdx.x * FBN;
    const int m0  = blockIdx.y * FBM;
    const int kstart = blockIdx.z * Klen;
    const int nch = Klen / FBK;
    float* Cout = C + (size_t)blockIdx.z * ((size_t)M * (size_t)N);

    const int srow = tid >> 2;
    const int kq   = tid & 3;

    float4 aR0, aR1, bR;

    auto loadChunk = [&](int kb0) {
        const int kc = kb0 + kq * 4;
        const float* ap; int ao, ld;
        if (kc < kA1)      { ap = A0; ao = kc;       ld = lda0; }
        else if (kc < kA2) { ap = A1; ao = kc - kA1; ld = lda1; }
        else               { ap = A2; ao = kc - kA2; ld = lda2; }
        const int r0 = m0 + srow, r1 = r0 + 64;
        aR0 = (r0 < M) ? *(const float4*)(ap + (size_t)r0 * ld + ao)
                       : make_float4(0.f, 0.f, 0.f, 0.f);
        aR1 = (r1 < M) ? *(const float4*)(ap + (size_t)r1 * ld + ao)
                       : make_float4(0.f, 0.f, 0.f, 0.f);
        const float* bp; int bo, bld;
        if (kc < kB1) { bp = B0; bo = kc;       bld = ldb0; }
        else          { bp = B1; bo = kc - kB1; bld = ldb1; }
        const int bn = n0 + srow;
        bR = (bn < N) ? *(const float4*)(bp + (size_t)bn * bld + bo)
                      : make_float4(0.f, 0.f, 0.f, 0.f);
    };
    auto storeChunk = [&](int bsel) {
        const int k4 = kq * 4;
        As[bsel][k4+0][srow]      = aR0.x;
        As[bsel][k4+1][srow]      = aR0.y;
        As[bsel][k4+2][srow]      = aR0.z;
        As[bsel][k4+3][srow]      = aR0.w;
        As[bsel][k4+0][srow + 64] = aR1.x;
        As[bsel][k4+1][srow + 64] = aR1.y;
        As[bsel][k4+2][srow + 64] = aR1.z;
        As[bsel][k4+3][srow + 64] = aR1.w;
        Bs[bsel][k4+0][srow]      = bR.x;
        Bs[bsel][k4+1][srow]      = bR.y;
        Bs[bsel][k4+2][srow]      = bR.z;
        Bs[bsel][k4+3][srow]      = bR.w;
    };

    float acc[8][4];
#pragma unroll
    for (int i = 0; i < 8; ++i)
#pragma unroll
        for (int j = 0; j < 4; ++j) acc[i][j] = 0.f;

    loadChunk(kstart);
    storeChunk(0);
    __syncthreads();
    int bsel = 0;
    for (int c = 0; c < nch; ++c) {
        if (c + 1 < nch) loadChunk(kstart + (c + 1) * FBK);
#pragma unroll
        for (int kkk = 0; kkk < FBK; ++kkk) {
            float a[8], b[4];
            const float4 av0 = *(const float4*)&As[bsel][kkk][ty * 8];
            const float4 av1 = *(const float4*)&As[bsel][kkk][ty * 8 + 4];
            a[0]=av0.x; a[1]=av0.y; a[2]=av0.z; a[3]=av0.w;
            a[4]=av1.x; a[5]=av1.y; a[6]=av1.z; a[7]=av1.w;
            const float2 bv0 = *(const float2*)&Bs[bsel][kkk][tx * 2];
            const float2 bv1 = *(const float2*)&Bs[bsel][kkk][tx * 2 + 32];
            b[0]=bv0.x; b[1]=bv0.y; b[2]=bv1.x; b[3]=bv1.y;
#pragma unroll
            for (int i = 0; i < 8; ++i)
#pragma unroll
                for (int j = 0; j < 4; ++j)
                    acc[i][j] = fmaf(a[i], b[j], acc[i][j]);
        }
        if (c + 1 < nch) storeChunk(bsel ^ 1);
        __syncthreads();
        bsel ^= 1;
    }

#pragma unroll
    for (int i = 0; i < 8; ++i) {
        const int row = m0 + ty * 8 + i;
        if (row >= M) continue;
        const size_t rbase = (size_t)row * N;
#pragma unroll
        for (int g = 0; g < 2; ++g) {
            const int col = n0 + tx * 2 + g * 32;
            if (col + 1 < N) {
                float2 st; st.x = acc[i][g*2+0]; st.y = acc[i][g*2+1];
                *(float2*)(Cout + rbase + col) = st;
            } else if (col < N) {
                Cout[rbase + col] = acc[i][g*2+0];
            }
        }
    }
}

// ---------------------------------------------------------------------------
__global__ void ij_bias_kernel(const float* __restrict__ b_ih, const float* __restrict__ b_hh,
                               float* __restrict__ bias)
{
    int i = blockIdx.x * 256 + threadIdx.x;
    if (i < G4) bias[i] = b_ih[i] + b_hh[i];
}

__global__ void ij_emb_kernel(const float* __restrict__ W_emb, const float* __restrict__ b_emb,
                              const int* __restrict__ pop_t, float* __restrict__ emb)
{
    int i = blockIdx.x * 256 + threadIdx.x;
    if (i >= BKR * EE) return;
    int r = i >> 7, e = i & 127;
    float v = W_emb[e * DD + pop_t[r]] + b_emb[e];
    emb[i] = v > 0.f ? v : 0.f;
}

// LSTM elementwise; fuses gate split-K reduce + xfW row-add + bias.
__global__ void ij_lstm_kernel(const float* __restrict__ z0, const float* __restrict__ z1,
                               const float* __restrict__ xfw, const float* __restrict__ bias,
                               const float* __restrict__ c,
                               float* __restrict__ h2, float* __restrict__ c2)
{
    int i = blockIdx.x * 256 + threadIdx.x;
    if (i >= BKR * HH) return;
    int r = i >> 11, hh = i & 2047;
    const size_t zb = (size_t)r * G4;
    const float* xw = xfw + (size_t)(r & 63) * G4;
    float iv = z0[zb + hh]        + z1[zb + hh]        + xw[hh]        + bias[hh];
    float fv = z0[zb + HH + hh]   + z1[zb + HH + hh]   + xw[HH + hh]   + bias[HH + hh];
    float gv = z0[zb + 2*HH + hh] + z1[zb + 2*HH + hh] + xw[2*HH + hh] + bias[2*HH + hh];
    float ov = z0[zb + 3*HH + hh] + z1[zb + 3*HH + hh] + xw[3*HH + hh] + bias[3*HH + hh];
    float si = 1.f / (1.f + expf(-iv));
    float sf = 1.f / (1.f + expf(-fv));
    float so = 1.f / (1.f + expf(-ov));
    float cv = sf * c[i] + si * tanhf(gv);
    c2[i] = cv;
    h2[i] = so * tanhf(cv);
}

// sums 8 split-K partials + bias + relu
__global__ void ij_reduce_fc1_kernel(const float* __restrict__ part, const float* __restrict__ b_fc1,
                                     float* __restrict__ hd)
{
    int i = blockIdx.x * 256 + threadIdx.x;
    if (i >= BKR * HH) return;
    float v = b_fc1[i & 2047];
#pragma unroll
    for (int s = 0; s < 8; ++s) v += part[(size_t)s * 1048576 + i];
    hd[i] = v > 0.f ? v : 0.f;
}

__global__ void ij_reduce_xfw_kernel(const float* __restrict__ part, float* __restrict__ xfw)
{
    int i = blockIdx.x * 256 + threadIdx.x;
    if (i >= BB * G4) return;
    xfw[i] = part[i] + part[i + 524288] + part[i + 1048576] + part[i + 1572864];
}

// ---------------------------------------------------------------------------
// Per-row: reduce 16 logits partials + b_out + mask row, log_softmax, greedy
// argmax, Gumbel-with-max conditioned g. All f64 (decision-critical).
// ---------------------------------------------------------------------------
__global__ __launch_bounds__(256)
void ij_softmax_g_kernel(const float* __restrict__ part, const float* __restrict__ b_out,
                         const float* __restrict__ mask_table, const int* __restrict__ pop_t,
                         const float* __restrict__ gum_t, const double* __restrict__ G,
                         const double* __restrict__ logp,
                         double* __restrict__ logp_tok, double* __restrict__ gmat,
                         int* __restrict__ greedy)
{
    const int r = blockIdx.x, tid = threadIdx.x;
    __shared__ double sred[256];
    __shared__ int    sidx[256];
    __shared__ double sbc[2];

    const int pop = pop_t[r];
    const int j0 = tid, j1 = tid + 256;
    double lg0 = -INFINITY, lg1 = -INFINITY;
    if (j0 < DD) {
        double v = (double)b_out[j0] + (double)mask_table[pop * DD + j0];
#pragma unroll
        for (int s = 0; s < 16; ++s) v += (double)part[(size_t)s * (BKR*DD) + (size_t)r * DD + j0];
        lg0 = v;
    }
    if (j1 < DD) {
        double v = (double)b_out[j1] + (double)mask_table[pop * DD + j1];
#pragma unroll
        for (int s = 0; s < 16; ++s) v += (double)part[(size_t)s * (BKR*DD) + (size_t)r * DD + j1];
        lg1 = v;
    }
    double mv = lg0; int mi = j0;
    if (lg1 > mv) { mv = lg1; mi = j1; }
    sred[tid] = mv; sidx[tid] = mi;
    __syncthreads();
    for (int off = 128; off > 0; off >>= 1) {
        if (tid < off) {
            double ov = sred[tid+off]; int oi = sidx[tid+off];
            if (ov > sred[tid] || (ov == sred[tid] && oi < sidx[tid])) { sred[tid] = ov; sidx[tid] = oi; }
        }
        __syncthreads();
    }
    if (tid == 0) { sbc[0] = sred[0]; greedy[r] = sidx[0]; }
    __syncthreads();
    const double rowmax = sbc[0];

    double es = 0.0;
    if (j0 < DD) es += exp(lg0 - rowmax);
    if (j1 < DD) es += exp(lg1 - rowmax);
    __syncthreads();
    sred[tid] = es;
    __syncthreads();
    for (int off = 128; off > 0; off >>= 1) {
        if (tid < off) sred[tid] += sred[tid+off];
        __syncthreads();
    }
    if (tid == 0) sbc[1] = log(sred[0]);
    __syncthreads();
    const double lse = sbc[1];
    const double lpr = logp[r], Gr = G[r];

    double gp0 = -INFINITY, gp1 = -INFINITY;
    if (j0 < DD) {
        double lt = lg0 - rowmax - lse;
        logp_tok[(size_t)r * DD + j0] = lt;
        double u = (double)gum_t[(size_t)r * DD + j0];
        u = fmin(fmax(u, 1e-9), 1.0 - 1e-9);
        gp0 = lt + lpr + (-log(-log(u)));
    }
    if (j1 < DD) {
        double lt = lg1 - rowmax - lse;
        logp_tok[(size_t)r * DD + j1] = lt;
        double u = (double)gum_t[(size_t)r * DD + j1];
        u = fmin(fmax(u, 1e-9), 1.0 - 1e-9);
        gp1 = lt + lpr + (-log(-log(u)));
    }
    __syncthreads();
    sred[tid] = fmax(gp0, gp1);
    __syncthreads();
    for (int off = 128; off > 0; off >>= 1) {
        if (tid < off) sred[tid] = fmax(sred[tid], sred[tid+off]);
        __syncthreads();
    }
    const double Z = sred[0];
    if (j0 < DD) {
        double v = Gr - gp0 + log1p(-exp(gp0 - Z));
        gmat[(size_t)r * DD + j0] = Gr - fmax(v, 0.0) - log1p(exp(-fabs(v)));
    }
    if (j1 < DD) {
        double v = Gr - gp1 + log1p(-exp(gp1 - Z));
        gmat[(size_t)r * DD + j1] = Gr - fmax(v, 0.0) - log1p(exp(-fabs(v)));
    }
}

// ---------------------------------------------------------------------------
// One block per image b: top-8 of 3200 (desc, low index on tie), bookkeeping.
// ---------------------------------------------------------------------------
__global__ __launch_bounds__(256)
void ij_beam_kernel(const double* __restrict__ gmat, const double* __restrict__ logp_tok,
                    const int* __restrict__ greedy, const int* __restrict__ pop_t,
                    const float* __restrict__ mask_table,
                    double* __restrict__ G, double* __restrict__ logp,
                    double* __restrict__ samples, double* __restrict__ outs,
                    double* __restrict__ entacc, double* __restrict__ wpq,
                    double* __restrict__ lgp_o, int* __restrict__ order_g, int t)
{
    const int b = blockIdx.x, tid = threadIdx.x;
    __shared__ double sv[256];
    __shared__ int    si2[256];
    __shared__ double gval8[8];
    __shared__ int    gidx8[8];
    __shared__ int    ord8[8], smp8[8];
    __shared__ double lp28[8], sel8[8], Gn8[8];
    __shared__ double oldS[8][TT], oldO[8][TT];
    __shared__ double efull[8];

    if (t > 0) {
        for (int pass = 0; pass < 8; ++pass) {
            double bv = -INFINITY; int bi = 0x7fffffff;
            for (int cand = tid; cand < KK * DD; cand += 256) {
                bool used = false;
                for (int p = 0; p < pass; ++p) used |= (gidx8[p] == cand);
                if (used) continue;
                int kb2 = cand / DD, d = cand - kb2 * DD;
                double v = gmat[(size_t)(kb2 * BB + b) * DD + d];
                if (v > bv || (v == bv && cand < bi)) { bv = v; bi = cand; }
            }
            sv[tid] = bv; si2[tid] = bi;
            __syncthreads();
            for (int off = 128; off > 0; off >>= 1) {
                if (tid < off) {
                    double ov = sv[tid+off]; int oi = si2[tid+off];
                    if (ov > sv[tid] || (ov == sv[tid] && oi < si2[tid])) { sv[tid] = ov; si2[tid] = oi; }
                }
                __syncthreads();
            }
            if (tid == 0) { gval8[pass] = sv[0]; gidx8[pass] = si2[0]; }
            __syncthreads();
        }
    }

    if (tid < 8) {
        const int s = tid, rp = s * BB + b;
        int ord, smp; double Gn;
        if (t == 0) { ord = rp; smp = greedy[rp]; Gn = G[rp]; }
        else {
            int idx = gidx8[s]; int kb2 = idx / DD;
            ord = kb2 * BB + b; smp = idx - kb2 * DD; Gn = gval8[s];
        }
        ord8[s] = ord; smp8[s] = smp; Gn8[s] = Gn;
        double sel = logp_tok[(size_t)ord * DD + smp];
        double lp2 = (t == 0) ? logp[ord] : logp[ord] + sel;
        sel8[s] = sel; lp28[s] = lp2;
    }
    __syncthreads();
    if (tid < 8 * TT) {
        int s = tid / TT, ttc = tid - s * TT;
        oldS[s][ttc] = samples[ord8[s] * TT + ttc];
        oldO[s][ttc] = outs[ord8[s] * TT + ttc];
    }
    __syncthreads();
    if (tid < 8 * TT) {
        int s = tid / TT, ttc = tid - s * TT;
        int rp = s * BB + b;
        samples[rp * TT + ttc] = (ttc == t) ? (double)smp8[s] : oldS[s][ttc];
        outs[rp * TT + ttc]    = (ttc == t) ? sel8[s]         : oldO[s][ttc];
    }
    if (tid >= 96 && tid < 104) {
        int s = tid - 96, rp = s * BB + b;
        G[rp]       = Gn8[s];
        logp[rp]    = lp28[s];
        order_g[rp] = ord8[s];
    }

    if (t > 0) {
        for (int s = 0; s < KK - 1; ++s) {
            const int ord = ord8[s];
            const double* lrow = logp_tok + (size_t)ord * DD;
            const float*  mrow = mask_table + (size_t)pop_t[ord] * DD;
            double acc = 0.0;
            for (int j = tid; j < DD; j += 256) {
                double lp_ = lrow[j];
                if (mrow[j] == 0.0f) acc += lp_ * exp(lp_);
            }
            __syncthreads();
            sv[tid] = acc;
            __syncthreads();
            for (int off = 128; off > 0; off >>= 1) {
                if (tid < off) sv[tid] += sv[tid+off];
                __syncthreads();
            }
            if (tid == 0) efull[s] = sv[0];
            __syncthreads();
        }
        if (tid == 0) {
            const double gk = gval8[7];
            double sw = 0.0, swe = 0.0;
            for (int s = 0; s < KK - 1; ++s) {
                double phi = lp28[s];
                double x = gk - phi;
                double y = exp(-x);
                double gls;
                if (x >= 10.0) gls = -x - y * 0.5 + y * y * (1.0 / 24.0);
                else           gls = log(-expm1(-exp(-fmin(x, 10.0))));
                double w = exp(phi - gls);
                wpq[b * (KK-1) + s]   = w;
                lgp_o[b * (KK-1) + s] = phi;
                sw += w; swe += w * efull[s];
            }
            entacc[b] += swe / sw;
        }
    }
}

__global__ void ij_permute_kernel(const float* __restrict__ h2, const float* __restrict__ c2,
                                  const int* __restrict__ order_g,
                                  float* __restrict__ h, float* __restrict__ c)
{
    int i = blockIdx.x * 256 + threadIdx.x;
    if (i >= BKR * HH) return;
    int r = i >> 11, j = i & 2047;
    int o = order_g[r];
    h[i] = h2[(size_t)o * HH + j];
    c[i] = c2[(size_t)o * HH + j];
}

__global__ void ij_final_kernel(const double* __restrict__ outs, const double* __restrict__ samples,
                                const double* __restrict__ entacc, const double* __restrict__ wpq,
                                const double* __restrict__ lgp_o, float* __restrict__ out)
{
    int i = blockIdx.x * 256 + threadIdx.x;
    if (i < 5376) {
        int bb = i / 84, rest = i - bb * 84;
        int s = rest / TT, ttc = rest - s * TT;
        size_t src = (size_t)(s * BB + bb) * TT + ttc;
        out[i]        = (float)outs[src];
        out[5376 + i] = (float)samples[src];
    } else if (i < 5440) {
        out[10752 + (i - 5376)] = (float)entacc[i - 5376];
    } else if (i < 5888) {
        int q = i - 5440; out[10816 + q] = (float)wpq[q];
    } else if (i < 6336) {
        int q = i - 5888; out[11264 + q] = (float)lgp_o[q];
    }
}

// ---------------------------------------------------------------------------
extern "C" void kernel_launch(void* const* d_in, const int* in_sizes, int n_in,
                              void* d_out, int out_size, void* d_ws, size_t ws_size,
                              hipStream_t stream)
{
    const float* x_f   = (const float*)d_in[0];
    const float* x_f3  = (const float*)d_in[1];
    const float* gum   = (const float*)d_in[2];
    const int*   pop   = (const int*)d_in[3];
    const float* mask  = (const float*)d_in[4];
    const float* W_emb = (const float*)d_in[5];
    const float* b_emb = (const float*)d_in[6];
    const float* W_ih  = (const float*)d_in[7];
    const float* W_hh  = (const float*)d_in[8];
    const float* b_ih  = (const float*)d_in[9];
    const float* b_hh  = (const float*)d_in[10];
    const float* W_fc1 = (const float*)d_in[11];
    const float* b_fc1 = (const float*)d_in[12];
    const float* W_out = (const float*)d_in[13];
    const float* b_out = (const float*)d_in[14];
    float* out = (float*)d_out;
    char*  ws  = (char*)d_ws;

    if (ws_size < WS_TOTAL) return;

    double* STATE = (double*)(ws + OFF_STATE);
    double* Gv    = STATE + SI_G;
    double* LOGP  = STATE + SI_LOGP;
    double* SAMP  = STATE + SI_SAMP;
    double* OUTS  = STATE + SI_OUTS;
    double* ENT   = STATE + SI_ENT;
    double* WPQ   = STATE + SI_WPQ;
    double* LGP   = STATE + SI_LGP;
    float*  H     = (float*)(ws + OFF_H);
    float*  Cc    = (float*)(ws + OFF_C);
    float*  Z     = (float*)(ws + OFF_Z);
    float*  Z1    = Z + (size_t)BKR * G4;
    float*  H2    = (float*)(ws + OFF_H2);
    float*  C2    = (float*)(ws + OFF_C2);
    float*  HD    = (float*)(ws + OFF_HD);
    float*  EMB   = (float*)(ws + OFF_EMB);
    float*  XFW   = (float*)(ws + OFF_XFW);
    float*  BIAS  = (float*)(ws + OFF_BIAS);
    double* LPT   = (double*)(ws + OFF_LPT);
    double* GMAT  = (double*)(ws + OFF_GMAT);
    int*    ORDER = (int*)(ws + OFF_INTS);
    int*    GREEDY= ORDER + 512;

    hipMemsetAsync(ws, 0, ZERO_END, stream);
    ij_bias_kernel<<<32, 256, 0, stream>>>(b_ih, b_hh, BIAS);

    // xfW = x_f @ W_ih[:, :2048]^T  (one-time, fp32 vector GEMM, M=64)
    ij_gemm_f32<<<dim3(128, 1, 4), 256, 0, stream>>>(
        x_f, nullptr, nullptr, 1 << 30, 1 << 30, 2048, 0, 0,
        W_ih, nullptr, 1 << 30, 4224, 0,
        Z, BB, G4, 512);
    ij_reduce_xfw_kernel<<<2048, 256, 0, stream>>>(Z, XFW);

    for (int t = 0; t < TT; ++t) {
        const int* pop_t = pop + t * BKR;
        ij_emb_kernel<<<256, 256, 0, stream>>>(W_emb, b_emb, pop_t, EMB);

        // gate GEMM (DMA MFMA): A=[emb|xf3_t|h], B=[W_ih cols 2048..|W_hh]
        // split-K=2 partials; lstm fuses reduce + xfW + bias.
        ij_gemm_dma<<<dim3(64, 4, 2), 256, 0, stream>>>(
            EMB, x_f3 + (size_t)t * BKR * 2048, H, 128, 2176, 128, 2048,
            W_ih + 2048, W_hh, 2176, 4224, 2048,
            Z, G4, 2112);

        ij_lstm_kernel<<<4096, 256, 0, stream>>>(Z, Z1, XFW, BIAS, Cc, H2, C2);

        // fc1 (DMA MFMA, split-K=8; reduce w/ bias+relu)
        ij_gemm_dma<<<dim3(16, 4, 8), 256, 0, stream>>>(
            H2, nullptr, nullptr, 1 << 30, 1 << 30, 2048, 2048,
            W_fc1, nullptr, 1 << 30, 2048, 2048,
            Z, HH, 256);
        ij_reduce_fc1_kernel<<<4096, 256, 0, stream>>>(Z, b_fc1, HD);

        // logits (DMA MFMA, split-K=16; reduce folded into softmax kernel)
        ij_gemm_dma<<<dim3(4, 4, 16), 256, 0, stream>>>(
            HD, nullptr, nullptr, 1 << 30, 1 << 30, 2048, 2048,
            W_out, nullptr, 1 << 30, 2048, 2048,
            Z, DD, 128);

        ij_softmax_g_kernel<<<512, 256, 0, stream>>>(
            Z, b_out, mask, pop_t, gum + (size_t)t * BKR * DD,
            Gv, LOGP, LPT, GMAT, GREEDY);

        ij_beam_kernel<<<64, 256, 0, stream>>>(
            GMAT, LPT, GREEDY, pop_t, mask,
            Gv, LOGP, SAMP, OUTS, ENT, WPQ, LGP, ORDER, t);

        ij_permute_kernel<<<4096, 256, 0, stream>>>(H2, C2, ORDER, H, Cc);
    }

    ij_final_kernel<<<25, 256, 0, stream>>>(OUTS, SAMP, ENT, WPQ, LGP, out);
    (void)in_sizes; (void)n_in; (void)out_size;
}